// Round 1
// baseline (127.674 us; speedup 1.0000x reference)
//
#include <hip/hip_runtime.h>

// Problem constants: B=4, L=512, D=128, C=128
#define NB 4
#define SL 512
#define DD 128
#define CC 128

__device__ __forceinline__ float fexp2(float x) { return __builtin_amdgcn_exp2f(x); }
__device__ __forceinline__ float frcp(float x)  { return __builtin_amdgcn_rcpf(x); }

// Kernel 1: projections.
//   p2 [B*L, C]   = 2*log2(e) * (inps @ wei_t + bxh)     (query side, i-indexed)
//   k2T [B, C, L] = 2*log2(e) * (inps @ wei_x)^T         (key side, transposed for
//                                                          coalesced j-reads in kernel 2)
// One block per 8 rows; threads 0-127 do wei_t column c, threads 128-255 do wei_x.
// inps row values are block-uniform -> compiler emits s_loads; weight loads coalesced.
__global__ __launch_bounds__(256) void proj_kernel(
    const float* __restrict__ inps, const float* __restrict__ wei_t,
    const float* __restrict__ wei_x, const float* __restrict__ bxh,
    float* __restrict__ p2, float* __restrict__ k2T)
{
    const float K2 = 2.8853900817779268f;  // 2*log2(e)
    int row0 = blockIdx.x * 8;             // global row = b*SL + i
    int b    = row0 / SL;
    int c    = threadIdx.x & 127;
    int sel  = threadIdx.x >> 7;           // 0 -> wei_t, 1 -> wei_x
    const float* W = sel ? wei_x : wei_t;
    const float* inrow = inps + (size_t)row0 * DD;

    float acc[8] = {0.f,0.f,0.f,0.f,0.f,0.f,0.f,0.f};
    for (int k = 0; k < DD; ++k) {
        float w = W[k * CC + c];
        #pragma unroll
        for (int r = 0; r < 8; ++r)
            acc[r] = fmaf(inrow[r * DD + k], w, acc[r]);
    }

    if (sel == 0) {
        float bb = bxh[c];
        #pragma unroll
        for (int r = 0; r < 8; ++r)
            p2[(size_t)(row0 + r) * CC + c] = K2 * (acc[r] + bb);
    } else {
        int i0 = row0 - b * SL;
        #pragma unroll
        for (int r = 0; r < 8; ++r)
            k2T[((size_t)b * CC + c) * SL + (i0 + r)] = K2 * acc[r];
    }
}

// Kernel 2: one block per (b, i). Fused scores -> softmax -> A@V.
// scores'[j] = sum_c (-2*wa[c]) / (exp2(p2[i,c] + k2T[c,j]) + 1)
//   (the constant  sum_c wa[c] + bxa  is uniform over j -> dropped; softmax is
//    shift-invariant, so the result is identical)
__global__ __launch_bounds__(256) void attn_kernel(
    const float* __restrict__ inps, const float* __restrict__ wei_a,
    const float* __restrict__ p2, const float* __restrict__ k2T,
    float* __restrict__ out)
{
    __shared__ float p2s[CC];
    __shared__ float wa2s[CC];
    __shared__ float sc[SL];        // scores, then attention weights a[j]
    __shared__ float redbuf[8 * DD];
    __shared__ float redw[8];       // per-wave partials: [0..3]=max, [4..7]=sum

    const int bi  = blockIdx.x;     // b*SL + i
    const int b   = bi >> 9;
    const int tid = threadIdx.x;

    // Phase A: stage query row + weight vector in LDS
    if (tid < CC) {
        p2s[tid]  = p2[(size_t)bi * CC + tid];
        wa2s[tid] = -2.0f * wei_a[tid];
    }
    __syncthreads();

    // Phase B: scores. Thread t handles j = 2t, 2t+1 (coalesced float2 loads of k2T).
    const int j0 = tid * 2;
    const float* kbase = k2T + (size_t)b * CC * SL;
    float s0 = 0.f, s1 = 0.f;
    for (int c = 0; c < CC; ++c) {
        float pc = p2s[c];
        float wc = wa2s[c];
        float2 kv = *reinterpret_cast<const float2*>(kbase + (size_t)c * SL + j0);
        float t0 = fexp2(pc + kv.x);
        float t1 = fexp2(pc + kv.y);
        s0 = fmaf(wc, frcp(t0 + 1.0f), s0);
        s1 = fmaf(wc, frcp(t1 + 1.0f), s1);
    }

    // Phase C: softmax over the 512 scores (2 per thread)
    const int lane = tid & 63, wv = tid >> 6;
    float m = fmaxf(s0, s1);
    #pragma unroll
    for (int off = 32; off > 0; off >>= 1)
        m = fmaxf(m, __shfl_xor(m, off, 64));
    if (lane == 0) redw[wv] = m;
    __syncthreads();
    m = fmaxf(fmaxf(redw[0], redw[1]), fmaxf(redw[2], redw[3]));

    const float LOG2E = 1.4426950408889634f;
    float e0 = fexp2((s0 - m) * LOG2E);
    float e1 = fexp2((s1 - m) * LOG2E);
    float ss = e0 + e1;
    #pragma unroll
    for (int off = 32; off > 0; off >>= 1)
        ss += __shfl_xor(ss, off, 64);
    if (lane == 0) redw[4 + wv] = ss;   // disjoint slots: no hazard with max reads
    __syncthreads();
    float S   = redw[4] + redw[5] + redw[6] + redw[7];
    float inv = frcp(S + 1e-7f);        // reference: a = e / (sum + eps)
    sc[j0]     = e0 * inv;
    sc[j0 + 1] = e1 * inv;
    __syncthreads();

    // Phase D: out[bi, :] = sum_j a[j] * inps[b, j, :]
    // Thread layout: d = (tid&31)*4 (float4), jq = tid>>5 -> 8-way split of j.
    const int dq = (tid & 31) * 4;
    const int jq = tid >> 5;
    const float* ibase = inps + (size_t)b * SL * DD;
    float4 acc = {0.f, 0.f, 0.f, 0.f};
    const int jb = jq * 64;
    for (int jj = 0; jj < 64; ++jj) {
        int j = jb + jj;
        float aj = sc[j];
        float4 v = *reinterpret_cast<const float4*>(ibase + (size_t)j * DD + dq);
        acc.x = fmaf(aj, v.x, acc.x);
        acc.y = fmaf(aj, v.y, acc.y);
        acc.z = fmaf(aj, v.z, acc.z);
        acc.w = fmaf(aj, v.w, acc.w);
    }
    *reinterpret_cast<float4*>(&redbuf[jq * DD + dq]) = acc;
    __syncthreads();
    if (tid < DD) {
        float sum = 0.f;
        #pragma unroll
        for (int q = 0; q < 8; ++q) sum += redbuf[q * DD + tid];
        out[(size_t)bi * DD + tid] = sum;
    }
}

extern "C" void kernel_launch(void* const* d_in, const int* in_sizes, int n_in,
                              void* d_out, int out_size, void* d_ws, size_t ws_size,
                              hipStream_t stream) {
    const float* inps  = (const float*)d_in[0];  // [B, L, D]
    const float* wei_t = (const float*)d_in[1];  // [D, C]
    const float* wei_x = (const float*)d_in[2];  // [D, C]
    const float* bxh   = (const float*)d_in[3];  // [C]
    const float* wei_a = (const float*)d_in[4];  // [C]
    // d_in[5] = bxa (scalar): dropped — uniform shift before softmax.
    float* out = (float*)d_out;                  // [B, L, D] fp32

    float* p2  = (float*)d_ws;                   // [B*L, C]   1 MB
    float* k2T = p2 + (size_t)NB * SL * CC;      // [B, C, L]  1 MB

    proj_kernel<<<NB * SL / 8, 256, 0, stream>>>(inps, wei_t, wei_x, bxh, p2, k2T);
    attn_kernel<<<NB * SL, 256, 0, stream>>>(inps, wei_a, p2, k2T, out);
}

// Round 2
// 112.199 us; speedup vs baseline: 1.1379x; 1.1379x over previous
//
#include <hip/hip_runtime.h>

// Problem constants: B=4, L=512, D=128, C=128
#define NB 4
#define SL 512
#define DD 128
#define CC 128

__device__ __forceinline__ float fexp2(float x) { return __builtin_amdgcn_exp2f(x); }
__device__ __forceinline__ float frcp(float x)  { return __builtin_amdgcn_rcpf(x); }

// Kernel 1: projections. 4 rows per block, 512 blocks (2/CU).
//   p2 [B*L, C]   = 2*log2(e) * (inps @ wei_t + bxh)
//   k2T [B, C, L] = 2*log2(e) * (inps @ wei_x)^T
// Threads 0-127: wei_t column c. Threads 128-255: wei_x column c.
// Input rows staged in LDS (broadcast reads, no conflict).
__global__ __launch_bounds__(256) void proj_kernel(
    const float* __restrict__ inps, const float* __restrict__ wei_t,
    const float* __restrict__ wei_x, const float* __restrict__ bxh,
    float* __restrict__ p2, float* __restrict__ k2T)
{
    __shared__ float lin[4 * DD];          // 4 input rows
    const float K2 = 2.8853900817779268f;  // 2*log2(e)
    const int row0 = blockIdx.x * 4;       // global row = b*SL + i
    const int b    = row0 >> 9;
    const int i0   = row0 & 511;
    const int tid  = threadIdx.x;
    const int c    = tid & 127;
    const int sel  = tid >> 7;             // 0 -> wei_t, 1 -> wei_x

    // stage 4 rows (256 threads x float2 = 512 floats)
    *reinterpret_cast<float2*>(&lin[tid * 2]) =
        *reinterpret_cast<const float2*>(&inps[(size_t)row0 * DD + tid * 2]);
    __syncthreads();

    const float* W = sel ? wei_x : wei_t;
    float a0 = 0.f, a1 = 0.f, a2 = 0.f, a3 = 0.f;
    #pragma unroll 4
    for (int k = 0; k < DD; ++k) {
        float w = W[k * CC + c];           // coalesced across c
        a0 = fmaf(lin[0 * DD + k], w, a0); // LDS broadcast
        a1 = fmaf(lin[1 * DD + k], w, a1);
        a2 = fmaf(lin[2 * DD + k], w, a2);
        a3 = fmaf(lin[3 * DD + k], w, a3);
    }

    if (sel == 0) {
        float bb = bxh[c];
        p2[(size_t)(row0 + 0) * CC + c] = K2 * (a0 + bb);
        p2[(size_t)(row0 + 1) * CC + c] = K2 * (a1 + bb);
        p2[(size_t)(row0 + 2) * CC + c] = K2 * (a2 + bb);
        p2[(size_t)(row0 + 3) * CC + c] = K2 * (a3 + bb);
    } else {
        // thread holds 4 consecutive-i values for its c -> one float4 store
        float4 v = {K2 * a0, K2 * a1, K2 * a2, K2 * a3};
        *reinterpret_cast<float4*>(&k2T[((size_t)b * CC + c) * SL + i0]) = v;
    }
}

// Kernel 2: one block per (b, 4 rows of i). 512 threads (8 waves), thread = j.
// scores'[i][j] = sum_c (-2*wa[c]) / (exp2(p2[i,c] + k2T[c,j]) + 1)
//   (constant sum_c wa[c] + bxa dropped: softmax shift-invariant)
// Each 4B kv load feeds 4 i-rows -> 4x arithmetic intensity vs 1-row blocks.
__global__ __launch_bounds__(512) void attn_kernel(
    const float* __restrict__ inps, const float* __restrict__ wei_a,
    const float* __restrict__ p2, const float* __restrict__ k2T,
    float* __restrict__ out)
{
    __shared__ float p2t[CC * 4];      // transposed: p2t[c*4+i] -> float4 read
    __shared__ float wa2s[CC];
    __shared__ float scT[SL * 4];      // a[i][j] stored [j][4] for float4 read
    __shared__ float redm[4 * 8];
    __shared__ float reds[4 * 8];
    __shared__ float redbuf[4 * 16 * DD];  // 32 KB phase-D partials

    const int blk = blockIdx.x;        // 512 blocks
    const int b   = blk >> 7;
    const int i0  = (blk & 127) * 4;
    const int bi0 = b * SL + i0;
    const int tid = threadIdx.x;
    const int j   = tid;               // 0..511
    const int lane = tid & 63, wv = tid >> 6;

    // Phase A: stage p2 rows (transposed) + weight vector
    {
        int c = tid >> 2, i = tid & 3;
        p2t[c * 4 + i] = p2[(size_t)(bi0 + i) * CC + c];
        if (tid < CC) wa2s[tid] = -2.0f * wei_a[tid];
    }
    __syncthreads();

    // Phase B: scores for 4 i's, this thread's j. Coalesced 4B kv loads.
    const float* kb = k2T + (size_t)b * CC * SL + j;
    float s0 = 0.f, s1 = 0.f, s2 = 0.f, s3 = 0.f;
    #pragma unroll 4
    for (int c = 0; c < CC; ++c) {
        float kv = kb[(size_t)c * SL];
        float4 pc = *reinterpret_cast<const float4*>(&p2t[c * 4]);  // broadcast
        float wc = wa2s[c];
        s0 = fmaf(wc, frcp(fexp2(pc.x + kv) + 1.0f), s0);
        s1 = fmaf(wc, frcp(fexp2(pc.y + kv) + 1.0f), s1);
        s2 = fmaf(wc, frcp(fexp2(pc.z + kv) + 1.0f), s2);
        s3 = fmaf(wc, frcp(fexp2(pc.w + kv) + 1.0f), s3);
    }

    // Phase C: softmax over j for each of the 4 rows
    float s[4] = {s0, s1, s2, s3};
    #pragma unroll
    for (int i = 0; i < 4; ++i) {
        float m = s[i];
        #pragma unroll
        for (int off = 32; off > 0; off >>= 1)
            m = fmaxf(m, __shfl_xor(m, off, 64));
        if (lane == 0) redm[i * 8 + wv] = m;
    }
    __syncthreads();
    const float LOG2E = 1.4426950408889634f;
    float e[4];
    #pragma unroll
    for (int i = 0; i < 4; ++i) {
        float m = redm[i * 8];
        #pragma unroll
        for (int q = 1; q < 8; ++q) m = fmaxf(m, redm[i * 8 + q]);
        e[i] = fexp2((s[i] - m) * LOG2E);
        float ss = e[i];
        #pragma unroll
        for (int off = 32; off > 0; off >>= 1)
            ss += __shfl_xor(ss, off, 64);
        if (lane == 0) reds[i * 8 + wv] = ss;
    }
    __syncthreads();
    {
        float4 av;
        float S0 = reds[0] + reds[1] + reds[2] + reds[3] + reds[4] + reds[5] + reds[6] + reds[7];
        av.x = e[0] * frcp(S0 + 1e-7f);
        float S1 = reds[8] + reds[9] + reds[10] + reds[11] + reds[12] + reds[13] + reds[14] + reds[15];
        av.y = e[1] * frcp(S1 + 1e-7f);
        float S2 = reds[16] + reds[17] + reds[18] + reds[19] + reds[20] + reds[21] + reds[22] + reds[23];
        av.z = e[2] * frcp(S2 + 1e-7f);
        float S3 = reds[24] + reds[25] + reds[26] + reds[27] + reds[28] + reds[29] + reds[30] + reds[31];
        av.w = e[3] * frcp(S3 + 1e-7f);
        *reinterpret_cast<float4*>(&scT[j * 4]) = av;   // a[i][j], [j][4] layout
    }
    __syncthreads();

    // Phase D: out[i0+i, :] = sum_j a[i][j] * inps[b, j, :], 4 rows at once.
    // Thread: dq=(tid&31)*4 (float4 of d), jq=tid>>5 (16-way j split).
    const int dq = (tid & 31) * 4;
    const int jq = tid >> 5;
    const float* ibase = inps + (size_t)b * SL * DD;
    float4 acc0 = {0,0,0,0}, acc1 = {0,0,0,0}, acc2 = {0,0,0,0}, acc3 = {0,0,0,0};
    const int jb = jq * 32;
    #pragma unroll 2
    for (int jj = 0; jj < 32; ++jj) {
        int jx = jb + jj;
        float4 v  = *reinterpret_cast<const float4*>(ibase + (size_t)jx * DD + dq);
        float4 a4 = *reinterpret_cast<const float4*>(&scT[jx * 4]);  // broadcast
        acc0.x = fmaf(a4.x, v.x, acc0.x); acc0.y = fmaf(a4.x, v.y, acc0.y);
        acc0.z = fmaf(a4.x, v.z, acc0.z); acc0.w = fmaf(a4.x, v.w, acc0.w);
        acc1.x = fmaf(a4.y, v.x, acc1.x); acc1.y = fmaf(a4.y, v.y, acc1.y);
        acc1.z = fmaf(a4.y, v.z, acc1.z); acc1.w = fmaf(a4.y, v.w, acc1.w);
        acc2.x = fmaf(a4.z, v.x, acc2.x); acc2.y = fmaf(a4.z, v.y, acc2.y);
        acc2.z = fmaf(a4.z, v.z, acc2.z); acc2.w = fmaf(a4.z, v.w, acc2.w);
        acc3.x = fmaf(a4.w, v.x, acc3.x); acc3.y = fmaf(a4.w, v.y, acc3.y);
        acc3.z = fmaf(a4.w, v.z, acc3.z); acc3.w = fmaf(a4.w, v.w, acc3.w);
    }
    *reinterpret_cast<float4*>(&redbuf[(0 * 16 + jq) * DD + dq]) = acc0;
    *reinterpret_cast<float4*>(&redbuf[(1 * 16 + jq) * DD + dq]) = acc1;
    *reinterpret_cast<float4*>(&redbuf[(2 * 16 + jq) * DD + dq]) = acc2;
    *reinterpret_cast<float4*>(&redbuf[(3 * 16 + jq) * DD + dq]) = acc3;
    __syncthreads();
    {
        int i = tid >> 7, d = tid & 127;
        float sum = 0.f;
        #pragma unroll
        for (int q = 0; q < 16; ++q) sum += redbuf[(i * 16 + q) * DD + d];
        out[(size_t)(bi0 + i) * DD + d] = sum;
    }
}

extern "C" void kernel_launch(void* const* d_in, const int* in_sizes, int n_in,
                              void* d_out, int out_size, void* d_ws, size_t ws_size,
                              hipStream_t stream) {
    const float* inps  = (const float*)d_in[0];  // [B, L, D]
    const float* wei_t = (const float*)d_in[1];  // [D, C]
    const float* wei_x = (const float*)d_in[2];  // [D, C]
    const float* bxh   = (const float*)d_in[3];  // [C]
    const float* wei_a = (const float*)d_in[4];  // [C]
    // d_in[5] = bxa (scalar): uniform shift before softmax -> dropped.
    float* out = (float*)d_out;                  // [B, L, D] fp32

    float* p2  = (float*)d_ws;                   // [B*L, C]   1 MB
    float* k2T = p2 + (size_t)NB * SL * CC;      // [B, C, L]  1 MB

    proj_kernel<<<NB * SL / 4, 256, 0, stream>>>(inps, wei_t, wei_x, bxh, p2, k2T);
    attn_kernel<<<NB * SL / 4, 512, 0, stream>>>(inps, wei_a, p2, k2T, out);
}

// Round 3
// 108.442 us; speedup vs baseline: 1.1773x; 1.0346x over previous
//
#include <hip/hip_runtime.h>

// Problem constants: B=4, L=512, D=128, C=128
#define NB 4
#define SL 512
#define DD 128
#define CC 128

__device__ __forceinline__ float fexp2(float x) { return __builtin_amdgcn_exp2f(x); }
__device__ __forceinline__ float frcp(float x)  { return __builtin_amdgcn_rcpf(x); }

// Kernel 1: projections. 2 rows/block, 1024 blocks (4/CU, 16 waves/CU).
//   p2 [B*L, C]   = 2*log2(e) * (inps @ wei_t + bxh)
//   k2T [B, C, L] = 2*log2(e) * (inps @ wei_x)^T
// Input-row reads are thread-uniform -> compiler emits s_load (SMEM pipe);
// W reads are coalesced vector loads; no LDS at all.
__global__ __launch_bounds__(256) void proj_kernel(
    const float* __restrict__ inps, const float* __restrict__ wei_t,
    const float* __restrict__ wei_x, const float* __restrict__ bxh,
    float* __restrict__ p2, float* __restrict__ k2T)
{
    const float K2 = 2.8853900817779268f;  // 2*log2(e)
    const int row0 = blockIdx.x * 2;       // global row = b*SL + i
    const int b    = row0 >> 9;
    const int i0   = row0 & 511;
    const int c    = threadIdx.x & 127;
    const int sel  = threadIdx.x >> 7;     // wave-uniform: waves 0-1 wei_t, 2-3 wei_x

    const float* W  = sel ? wei_x : wei_t;
    const float* r0 = inps + (size_t)row0 * DD;   // uniform -> s_load
    const float* r1 = r0 + DD;

    float a0 = 0.f, a1 = 0.f;
    #pragma unroll 8
    for (int k = 0; k < DD; ++k) {
        float w = W[k * CC + c];           // coalesced across c
        a0 = fmaf(r0[k], w, a0);
        a1 = fmaf(r1[k], w, a1);
    }

    if (sel == 0) {
        float bb = bxh[c];
        p2[(size_t)(row0 + 0) * CC + c] = K2 * (a0 + bb);
        p2[(size_t)(row0 + 1) * CC + c] = K2 * (a1 + bb);
    } else {
        float2 v = {K2 * a0, K2 * a1};
        *reinterpret_cast<float2*>(&k2T[((size_t)b * CC + c) * SL + i0]) = v;
    }
}

// Kernel 2: one block per (b, 4 rows of i). 512 threads, thread = j.
// scores'[i][j] = -2 * sum_c wa[c] / (exp2(p2[i,c] + k2T[c,j]) + 1)
//   (constant sum_c wa[c] + bxa dropped: softmax shift-invariant)
// p2 rows + wei_a are BLOCK-UNIFORM -> read straight from global with uniform
// addresses so the compiler emits batched s_load (SMEM pipe). No LDS traffic
// in the hot loop; only kv is a vector load (coalesced, L2-resident).
__global__ __launch_bounds__(512) void attn_kernel(
    const float* __restrict__ inps, const float* __restrict__ wei_a,
    const float* __restrict__ p2, const float* __restrict__ k2T,
    float* __restrict__ out)
{
    __shared__ float scT[SL * 4];          // a[i][j] stored [j][4]
    __shared__ float redm[4 * 8];
    __shared__ float reds[4 * 8];
    __shared__ float redbuf[4 * 16 * DD];  // 32 KB phase-D partials

    const int blk = blockIdx.x;            // 512 blocks
    const int b   = blk >> 7;
    const int i0  = (blk & 127) * 4;
    const int bi0 = b * SL + i0;
    const int tid = threadIdx.x;
    const int j   = tid;                   // 0..511
    const int lane = tid & 63, wv = tid >> 6;

    // Phase B: scores for 4 i's, this thread's j.
    const float* pr0 = p2 + (size_t)(bi0 + 0) * CC;  // uniform rows -> s_load
    const float* pr1 = p2 + (size_t)(bi0 + 1) * CC;
    const float* pr2 = p2 + (size_t)(bi0 + 2) * CC;
    const float* pr3 = p2 + (size_t)(bi0 + 3) * CC;
    const float* kb  = k2T + (size_t)b * CC * SL + j;

    float s0 = 0.f, s1 = 0.f, s2 = 0.f, s3 = 0.f;
    #pragma unroll 8
    for (int c = 0; c < CC; ++c) {
        float kv = kb[(size_t)c * SL];     // coalesced 4B/lane, L2-resident
        float wc = wei_a[c];               // uniform -> s_load
        s0 = fmaf(wc, frcp(fexp2(pr0[c] + kv) + 1.0f), s0);
        s1 = fmaf(wc, frcp(fexp2(pr1[c] + kv) + 1.0f), s1);
        s2 = fmaf(wc, frcp(fexp2(pr2[c] + kv) + 1.0f), s2);
        s3 = fmaf(wc, frcp(fexp2(pr3[c] + kv) + 1.0f), s3);
    }
    // fold the -2 factor of tanh once per row (dropped constant is uniform)
    float s[4] = {-2.f * s0, -2.f * s1, -2.f * s2, -2.f * s3};

    // Phase C: softmax over j for each of the 4 rows
    #pragma unroll
    for (int i = 0; i < 4; ++i) {
        float m = s[i];
        #pragma unroll
        for (int off = 32; off > 0; off >>= 1)
            m = fmaxf(m, __shfl_xor(m, off, 64));
        if (lane == 0) redm[i * 8 + wv] = m;
    }
    __syncthreads();
    const float LOG2E = 1.4426950408889634f;
    float e[4];
    #pragma unroll
    for (int i = 0; i < 4; ++i) {
        float m = redm[i * 8];
        #pragma unroll
        for (int q = 1; q < 8; ++q) m = fmaxf(m, redm[i * 8 + q]);
        e[i] = fexp2((s[i] - m) * LOG2E);
        float ss = e[i];
        #pragma unroll
        for (int off = 32; off > 0; off >>= 1)
            ss += __shfl_xor(ss, off, 64);
        if (lane == 0) reds[i * 8 + wv] = ss;
    }
    __syncthreads();
    {
        float4 av;
        float S0 = reds[0] + reds[1] + reds[2] + reds[3] + reds[4] + reds[5] + reds[6] + reds[7];
        av.x = e[0] * frcp(S0 + 1e-7f);
        float S1 = reds[8] + reds[9] + reds[10] + reds[11] + reds[12] + reds[13] + reds[14] + reds[15];
        av.y = e[1] * frcp(S1 + 1e-7f);
        float S2 = reds[16] + reds[17] + reds[18] + reds[19] + reds[20] + reds[21] + reds[22] + reds[23];
        av.z = e[2] * frcp(S2 + 1e-7f);
        float S3 = reds[24] + reds[25] + reds[26] + reds[27] + reds[28] + reds[29] + reds[30] + reds[31];
        av.w = e[3] * frcp(S3 + 1e-7f);
        *reinterpret_cast<float4*>(&scT[j * 4]) = av;   // a[i][j], [j][4] layout
    }
    __syncthreads();

    // Phase D: out[i0+i, :] = sum_j a[i][j] * inps[b, j, :], 4 rows at once.
    const int dq = (tid & 31) * 4;
    const int jq = tid >> 5;
    const float* ibase = inps + (size_t)b * SL * DD;
    float4 acc0 = {0,0,0,0}, acc1 = {0,0,0,0}, acc2 = {0,0,0,0}, acc3 = {0,0,0,0};
    const int jb = jq * 32;
    #pragma unroll 2
    for (int jj = 0; jj < 32; ++jj) {
        int jx = jb + jj;
        float4 v  = *reinterpret_cast<const float4*>(ibase + (size_t)jx * DD + dq);
        float4 a4 = *reinterpret_cast<const float4*>(&scT[jx * 4]);  // broadcast
        acc0.x = fmaf(a4.x, v.x, acc0.x); acc0.y = fmaf(a4.x, v.y, acc0.y);
        acc0.z = fmaf(a4.x, v.z, acc0.z); acc0.w = fmaf(a4.x, v.w, acc0.w);
        acc1.x = fmaf(a4.y, v.x, acc1.x); acc1.y = fmaf(a4.y, v.y, acc1.y);
        acc1.z = fmaf(a4.y, v.z, acc1.z); acc1.w = fmaf(a4.y, v.w, acc1.w);
        acc2.x = fmaf(a4.z, v.x, acc2.x); acc2.y = fmaf(a4.z, v.y, acc2.y);
        acc2.z = fmaf(a4.z, v.z, acc2.z); acc2.w = fmaf(a4.z, v.w, acc2.w);
        acc3.x = fmaf(a4.w, v.x, acc3.x); acc3.y = fmaf(a4.w, v.y, acc3.y);
        acc3.z = fmaf(a4.w, v.z, acc3.z); acc3.w = fmaf(a4.w, v.w, acc3.w);
    }
    *reinterpret_cast<float4*>(&redbuf[(0 * 16 + jq) * DD + dq]) = acc0;
    *reinterpret_cast<float4*>(&redbuf[(1 * 16 + jq) * DD + dq]) = acc1;
    *reinterpret_cast<float4*>(&redbuf[(2 * 16 + jq) * DD + dq]) = acc2;
    *reinterpret_cast<float4*>(&redbuf[(3 * 16 + jq) * DD + dq]) = acc3;
    __syncthreads();
    {
        int i = tid >> 7, d = tid & 127;
        float sum = 0.f;
        #pragma unroll
        for (int q = 0; q < 16; ++q) sum += redbuf[(i * 16 + q) * DD + d];
        out[(size_t)(bi0 + i) * DD + d] = sum;
    }
}

extern "C" void kernel_launch(void* const* d_in, const int* in_sizes, int n_in,
                              void* d_out, int out_size, void* d_ws, size_t ws_size,
                              hipStream_t stream) {
    const float* inps  = (const float*)d_in[0];  // [B, L, D]
    const float* wei_t = (const float*)d_in[1];  // [D, C]
    const float* wei_x = (const float*)d_in[2];  // [D, C]
    const float* bxh   = (const float*)d_in[3];  // [C]
    const float* wei_a = (const float*)d_in[4];  // [C]
    // d_in[5] = bxa (scalar): uniform shift before softmax -> dropped.
    float* out = (float*)d_out;                  // [B, L, D] fp32

    float* p2  = (float*)d_ws;                   // [B*L, C]   1 MB
    float* k2T = p2 + (size_t)NB * SL * CC;      // [B, C, L]  1 MB

    proj_kernel<<<NB * SL / 2, 256, 0, stream>>>(inps, wei_t, wei_x, bxh, p2, k2T);
    attn_kernel<<<NB * SL / 4, 512, 0, stream>>>(inps, wei_a, p2, k2T, out);
}

// Round 4
// 106.135 us; speedup vs baseline: 1.2029x; 1.0217x over previous
//
#include <hip/hip_runtime.h>

// Problem constants: B=4, L=512, D=128, C=128
#define NB 4
#define SL 512
#define DD 128
#define CC 128

__device__ __forceinline__ float fexp2(float x) { return __builtin_amdgcn_exp2f(x); }
__device__ __forceinline__ float frcp(float x)  { return __builtin_amdgcn_rcpf(x); }

// Kernel 1: projections. 2 rows/block, 1024 blocks.
//   p2 [B*L, C]   = 2*log2(e) * (inps @ wei_t + bxh)
//   k2T [B, C, L] = 2*log2(e) * (inps @ wei_x)^T
__global__ __launch_bounds__(256) void proj_kernel(
    const float* __restrict__ inps, const float* __restrict__ wei_t,
    const float* __restrict__ wei_x, const float* __restrict__ bxh,
    float* __restrict__ p2, float* __restrict__ k2T)
{
    const float K2 = 2.8853900817779268f;  // 2*log2(e)
    const int row0 = blockIdx.x * 2;       // global row = b*SL + i
    const int b    = row0 >> 9;
    const int i0   = row0 & 511;
    const int c    = threadIdx.x & 127;
    const int sel  = threadIdx.x >> 7;     // wave-uniform: waves 0-1 wei_t, 2-3 wei_x

    const float* W  = sel ? wei_x : wei_t;
    const float* r0 = inps + (size_t)row0 * DD;   // uniform -> s_load
    const float* r1 = r0 + DD;

    float a0 = 0.f, a1 = 0.f;
    #pragma unroll 8
    for (int k = 0; k < DD; ++k) {
        float w = W[k * CC + c];           // coalesced across c
        a0 = fmaf(r0[k], w, a0);
        a1 = fmaf(r1[k], w, a1);
    }

    if (sel == 0) {
        float bb = bxh[c];
        p2[(size_t)(row0 + 0) * CC + c] = K2 * (a0 + bb);
        p2[(size_t)(row0 + 1) * CC + c] = K2 * (a1 + bb);
    } else {
        float2 v = {K2 * a0, K2 * a1};
        *reinterpret_cast<float2*>(&k2T[((size_t)b * CC + c) * SL + i0]) = v;
    }
}

// Kernel 2: one block per (b, 2 rows of i). 512 threads, thread = j.
// 1024 blocks = 4 blocks/CU = 32 waves/CU (100% occupancy) — the round-3
// version at 512 blocks capped at 50% and starved the trans pipe.
// scores'[i][j] = -2 * sum_c wa[c] / (exp2(p2[i,c] + k2T[c,j]) + 1)
//   (constant sum_c wa[c] + bxa dropped: softmax shift-invariant)
__global__ __launch_bounds__(512, 8) void attn_kernel(
    const float* __restrict__ inps, const float* __restrict__ wei_a,
    const float* __restrict__ p2, const float* __restrict__ k2T,
    float* __restrict__ out)
{
    __shared__ float scT[SL * 2];          // a[i][j] stored [j][2]
    __shared__ float redm[2 * 8];
    __shared__ float reds[2 * 8];
    __shared__ float redbuf[2 * 16 * DD];  // 16 KB phase-D partials

    const int blk = blockIdx.x;            // 1024 blocks
    const int b   = blk >> 8;
    const int i0  = (blk & 255) * 2;
    const int bi0 = b * SL + i0;
    const int tid = threadIdx.x;
    const int j   = tid;                   // 0..511
    const int lane = tid & 63, wv = tid >> 6;

    // Phase B: scores for 2 i's, this thread's j. p2 rows + wei_a are
    // block-uniform -> s_load (SMEM pipe); kv is coalesced 4B/lane from L2.
    const float* pr0 = p2 + (size_t)(bi0 + 0) * CC;
    const float* pr1 = p2 + (size_t)(bi0 + 1) * CC;
    const float* kb  = k2T + (size_t)b * CC * SL + j;

    float s0 = 0.f, s1 = 0.f;
    #pragma unroll 16
    for (int c = 0; c < CC; ++c) {
        float kv = kb[(size_t)c * SL];
        float wc = wei_a[c];
        s0 = fmaf(wc, frcp(fexp2(pr0[c] + kv) + 1.0f), s0);
        s1 = fmaf(wc, frcp(fexp2(pr1[c] + kv) + 1.0f), s1);
    }
    float s[2] = {-2.f * s0, -2.f * s1};   // fold tanh's -2 once

    // Phase C: softmax over j for each of the 2 rows
    #pragma unroll
    for (int i = 0; i < 2; ++i) {
        float m = s[i];
        #pragma unroll
        for (int off = 32; off > 0; off >>= 1)
            m = fmaxf(m, __shfl_xor(m, off, 64));
        if (lane == 0) redm[i * 8 + wv] = m;
    }
    __syncthreads();
    const float LOG2E = 1.4426950408889634f;
    float e[2];
    #pragma unroll
    for (int i = 0; i < 2; ++i) {
        float m = redm[i * 8];
        #pragma unroll
        for (int q = 1; q < 8; ++q) m = fmaxf(m, redm[i * 8 + q]);
        e[i] = fexp2((s[i] - m) * LOG2E);
        float ss = e[i];
        #pragma unroll
        for (int off = 32; off > 0; off >>= 1)
            ss += __shfl_xor(ss, off, 64);
        if (lane == 0) reds[i * 8 + wv] = ss;
    }
    __syncthreads();
    {
        float2 av;
        float S0 = reds[0] + reds[1] + reds[2] + reds[3] + reds[4] + reds[5] + reds[6] + reds[7];
        av.x = e[0] * frcp(S0 + 1e-7f);
        float S1 = reds[8] + reds[9] + reds[10] + reds[11] + reds[12] + reds[13] + reds[14] + reds[15];
        av.y = e[1] * frcp(S1 + 1e-7f);
        *reinterpret_cast<float2*>(&scT[j * 2]) = av;   // a[i][j], [j][2] layout
    }
    __syncthreads();

    // Phase D: out[i0+i, :] = sum_j a[i][j] * inps[b, j, :], 2 rows at once.
    const int dq = (tid & 31) * 4;
    const int jq = tid >> 5;
    const float* ibase = inps + (size_t)b * SL * DD;
    float4 acc0 = {0,0,0,0}, acc1 = {0,0,0,0};
    const int jb = jq * 32;
    #pragma unroll 4
    for (int jj = 0; jj < 32; ++jj) {
        int jx = jb + jj;
        float4 v  = *reinterpret_cast<const float4*>(ibase + (size_t)jx * DD + dq);
        float2 a2 = *reinterpret_cast<const float2*>(&scT[jx * 2]);  // broadcast
        acc0.x = fmaf(a2.x, v.x, acc0.x); acc0.y = fmaf(a2.x, v.y, acc0.y);
        acc0.z = fmaf(a2.x, v.z, acc0.z); acc0.w = fmaf(a2.x, v.w, acc0.w);
        acc1.x = fmaf(a2.y, v.x, acc1.x); acc1.y = fmaf(a2.y, v.y, acc1.y);
        acc1.z = fmaf(a2.y, v.z, acc1.z); acc1.w = fmaf(a2.y, v.w, acc1.w);
    }
    *reinterpret_cast<float4*>(&redbuf[(0 * 16 + jq) * DD + dq]) = acc0;
    *reinterpret_cast<float4*>(&redbuf[(1 * 16 + jq) * DD + dq]) = acc1;
    __syncthreads();
    if (tid < 2 * DD) {
        int i = tid >> 7, d = tid & 127;
        float sum = 0.f;
        #pragma unroll
        for (int q = 0; q < 16; ++q) sum += redbuf[(i * 16 + q) * DD + d];
        out[(size_t)(bi0 + i) * DD + d] = sum;
    }
}

extern "C" void kernel_launch(void* const* d_in, const int* in_sizes, int n_in,
                              void* d_out, int out_size, void* d_ws, size_t ws_size,
                              hipStream_t stream) {
    const float* inps  = (const float*)d_in[0];  // [B, L, D]
    const float* wei_t = (const float*)d_in[1];  // [D, C]
    const float* wei_x = (const float*)d_in[2];  // [D, C]
    const float* bxh   = (const float*)d_in[3];  // [C]
    const float* wei_a = (const float*)d_in[4];  // [C]
    // d_in[5] = bxa (scalar): uniform shift before softmax -> dropped.
    float* out = (float*)d_out;                  // [B, L, D] fp32

    float* p2  = (float*)d_ws;                   // [B*L, C]   1 MB
    float* k2T = p2 + (size_t)NB * SL * CC;      // [B, C, L]  1 MB

    proj_kernel<<<NB * SL / 2, 256, 0, stream>>>(inps, wei_t, wei_x, bxh, p2, k2T);
    attn_kernel<<<NB * SL / 2, 512, 0, stream>>>(inps, wei_a, p2, k2T, out);
}